// Round 2
// baseline (121.066 us; speedup 1.0000x reference)
//
#include <hip/hip_runtime.h>
#include <stdint.h>

#define BATCH 32
#define NBOX 8192
#define NGT 128
#define M (NBOX + NGT)     // 8320
#define K_OUT 512
#define MAX_FG 128
#define C_CAP 256          // kth boundary-bucket members (~npos/1024, Poisson)
#define S_CAP 256          // selp members (<= 128 + value-ties)
#define U_CAP 1024         // neg union (<= 512 + boundary bucket ~nneg/1024)

// Monotone clamped bucket: v1>v2 => bkt(v1)>=bkt(v2); bkt(v1)>bkt(v2) => v1>v2.
__device__ __forceinline__ unsigned int bkt1024(float ns) {
    unsigned int u = (unsigned int)(ns * 16777216.0f) >> 14;
    return u > 1023u ? 1023u : u;
}

// Wave-aggregated compaction: one atomic per wave instead of one per item.
// Order within the list changes vs per-item atomics, but all consumers are
// order-independent (pairwise/value ranks); overflow beyond cap is the only
// order-sensitive case and is statistically impossible (verified prior runs).
template <typename F>
__device__ __forceinline__ void wave_compact(bool pred, unsigned int* ctr,
                                             unsigned int cap, F writer) {
    unsigned long long mb = __ballot(pred);
    if (!mb) return;                       // wave-uniform
    const int lane = threadIdx.x & 63;
    const int leader = __ffsll((unsigned long long)mb) - 1;
    unsigned int base = 0;
    if (lane == leader) base = atomicAdd(ctr, (unsigned int)__popcll(mb));
    base = __shfl(base, leader, 64);
    if (pred) {
        unsigned int slot = base + (unsigned int)__popcll(mb & ((1ull << lane) - 1ull));
        if (slot < cap) writer(slot);
    }
}

// ---------------------------------------------------------------------------
// Kernel 1: per (b, m) max IoU over 128 gt boxes + argmax, packed u16:
//   packed[b*M+m] = argmax(7b) | neg<<8 | pos<<9
// v2: gt boxes read straight from global with block-uniform index -> compiler
// scalarizes to s_load (K$), removing the per-iter LDS broadcast reads that
// were the binding pipe. gt area recomputed with the IDENTICAL __f*_rn
// sequence (bit-exact vs staged version). 128-thr blocks x 65/batch = exact
// coverage, no barrier, gt-row branch block-uniform.
// Exact __fdiv_rn kept: rounded-quotient ordering is semantically observable.
// ---------------------------------------------------------------------------
__global__ __launch_bounds__(128) void iou_kernel(
    const float* __restrict__ boxes,      // [B, NBOX, 4]
    const float* __restrict__ gt_boxes,   // [B, NGT, 4]
    unsigned short* __restrict__ packed)  // [B, M]
{
    const int b = blockIdx.x / 65;
    const int m = (blockIdx.x % 65) * 128 + threadIdx.x;   // [0, 8320)

    const float4* __restrict__ gt4 = (const float4*)gt_boxes + b * NGT;

    float4 bb = (m < NBOX) ? ((const float4*)boxes)[b * NBOX + m]
                           : gt4[m - NBOX];
    float b_area = __fmul_rn(__fsub_rn(bb.z, bb.x), __fsub_rn(bb.w, bb.y));

    float best = -1e30f;
    int bidx = 0;
    #pragma unroll 8
    for (int g = 0; g < NGT; ++g) {
        float4 gg = gt4[g];                       // uniform -> s_load
        float ga = __fmul_rn(__fsub_rn(gg.z, gg.x), __fsub_rn(gg.w, gg.y));
        float iymin = fmaxf(bb.x, gg.x);
        float ixmin = fmaxf(bb.y, gg.y);
        float iymax = fminf(bb.z, gg.z);
        float ixmax = fminf(bb.w, gg.w);
        float ia  = __fmul_rn(fmaxf(__fsub_rn(iymax, iymin), 0.0f),
                              fmaxf(__fsub_rn(ixmax, ixmin), 0.0f));
        float den = __fsub_rn(__fadd_rn(b_area, ga), ia);
        float iou = __fdiv_rn(ia, den);
        if (iou > best) { best = iou; bidx = g; }        // first-max = argmax
    }
    bool pos = best > 0.5f;
    bool neg = (best >= 0.0f) && (best < 0.5f);
    packed[b * M + m] = (unsigned short)(bidx | (neg ? 256 : 0) | (pos ? 512 : 0));
}

// ---------------------------------------------------------------------------
// Kernel 2: one block (1024 thr) per batch.
// v2: each thread register-caches its own chunk's 8 noise values + pos/neg
// masks during the load pass (chunk c = tid; tail chunks 1024..1039 handled
// via LDS by tid<16 lanes). Collection passes use registers (static unroll,
// no runtime indexing -> no scratch), killing the stride-8 scattered LDS
// reads. Union compaction uses ballot aggregation (64x fewer same-address
// atomics). Union rank inner loop reads 4 keys per LDS op (uint4/ushort4,
// padded; pad key=0 & m=0xFFFF never counts). All ordering on exact keys.
// ---------------------------------------------------------------------------
__global__ __launch_bounds__(1024) void select_kernel(
    const float* __restrict__ boxes,
    const float* __restrict__ gt_boxes,
    const int*   __restrict__ gt_labels,
    const float* __restrict__ noise,      // [B, M]
    const unsigned short* __restrict__ packed,
    float* __restrict__ out)
{
    const int b = blockIdx.x;
    const int tid = threadIdx.x;

    __shared__ float sh_ns[M];                 // 33280 B
    __shared__ unsigned int hist[1024];        // neg hist, 4096 B
    __shared__ unsigned int hist2[1024];       // pos hist, 4096 B
    __shared__ unsigned char posmask[M / 8];   // 1040 B
    __shared__ unsigned char negmask[M / 8];   // 1040 B
    __shared__ float4 sgt[NGT];                // 2048 B
    __shared__ int slab[NGT];                  // 512 B
    __shared__ float C[C_CAP];                 // 1024 B
    __shared__ unsigned short slist[S_CAP];    // 512 B
    __shared__ __align__(16) unsigned int   ukey[U_CAP + 4];  // 4112 B
    __shared__ __align__(16) unsigned short um[U_CAP + 4];    // 2056 B
    __shared__ unsigned int sh_Bp, sh_needp, sh_cc, sh_n1a, sh_B, sh_cnt, sh_kth;

    float* out_bt  = out;
    float* out_cls = out + BATCH * K_OUT * 4;
    float* out_roi = out + BATCH * K_OUT * 5;
    float* out_p2l = out + BATCH * K_OUT * 9;

    // ---- init + stage gt ---------------------------------------------------
    hist[tid] = 0;
    hist2[tid] = 0;
    if (tid == 0) { sh_cc = 0; sh_n1a = 0; sh_B = 0; sh_cnt = 0; sh_kth = 0xBF800000u; }
    if (tid < NGT) {
        sgt[tid]  = ((const float4*)gt_boxes)[b * NGT + tid];
        slab[tid] = gt_labels[b * NGT + tid];
    }
    __syncthreads();

    // ---- load pass: noise -> LDS + regs, masks + two histograms ------------
    float f[8];                                // this thread's chunk (c = tid)
    unsigned int pb = 0, nb = 0;
    {
        const uint4*  pk4 = (const uint4*)(packed + (size_t)b * M);  // 8 u16/load
        const float4* ns4 = (const float4*)(noise + (size_t)b * M);
        // main chunk: c = tid (all 1024 threads)
        {
            uint4 pv = pk4[tid];
            float4 n0 = ns4[2 * tid], n1v = ns4[2 * tid + 1];
            ((float4*)sh_ns)[2 * tid] = n0;
            ((float4*)sh_ns)[2 * tid + 1] = n1v;
            f[0] = n0.x; f[1] = n0.y; f[2] = n0.z; f[3] = n0.w;
            f[4] = n1v.x; f[5] = n1v.y; f[6] = n1v.z; f[7] = n1v.w;
            unsigned short e[8];
            e[0] = (unsigned short)(pv.x & 0xFFFF); e[1] = (unsigned short)(pv.x >> 16);
            e[2] = (unsigned short)(pv.y & 0xFFFF); e[3] = (unsigned short)(pv.y >> 16);
            e[4] = (unsigned short)(pv.z & 0xFFFF); e[5] = (unsigned short)(pv.z >> 16);
            e[6] = (unsigned short)(pv.w & 0xFFFF); e[7] = (unsigned short)(pv.w >> 16);
            #pragma unroll
            for (int k = 0; k < 8; ++k) {
                if (e[k] & 512) {
                    pb |= (1u << k);
                    atomicAdd(&hist2[bkt1024(f[k])], 1u);
                } else if (e[k] & 256) {
                    nb |= (1u << k);
                    atomicAdd(&hist[bkt1024(f[k])], 1u);
                }
            }
            posmask[tid] = (unsigned char)pb;
            negmask[tid] = (unsigned char)nb;
        }
        // tail chunks: c = 1024 + tid for tid < 16
        if (tid < 16) {
            int c = 1024 + tid;
            uint4 pv = pk4[c];
            float4 n0 = ns4[2 * c], n1v = ns4[2 * c + 1];
            ((float4*)sh_ns)[2 * c] = n0;
            ((float4*)sh_ns)[2 * c + 1] = n1v;
            float ft[8] = {n0.x, n0.y, n0.z, n0.w, n1v.x, n1v.y, n1v.z, n1v.w};
            unsigned short e[8];
            e[0] = (unsigned short)(pv.x & 0xFFFF); e[1] = (unsigned short)(pv.x >> 16);
            e[2] = (unsigned short)(pv.y & 0xFFFF); e[3] = (unsigned short)(pv.y >> 16);
            e[4] = (unsigned short)(pv.z & 0xFFFF); e[5] = (unsigned short)(pv.z >> 16);
            e[6] = (unsigned short)(pv.w & 0xFFFF); e[7] = (unsigned short)(pv.w >> 16);
            unsigned int pb2 = 0, nb2 = 0;
            #pragma unroll
            for (int k = 0; k < 8; ++k) {
                if (e[k] & 512) {
                    pb2 |= (1u << k);
                    atomicAdd(&hist2[bkt1024(ft[k])], 1u);
                } else if (e[k] & 256) {
                    nb2 |= (1u << k);
                    atomicAdd(&hist[bkt1024(ft[k])], 1u);
                }
            }
            posmask[c] = (unsigned char)pb2;
            negmask[c] = (unsigned char)nb2;
        }
    }
    __syncthreads();

    // ---- suffix scans: wave 0 -> hist (neg), wave 1 -> hist2 (pos) ---------
    {
        const int wv = tid >> 6, ln = tid & 63;
        if (wv < 2) {
            unsigned int* H = wv ? hist2 : hist;
            unsigned int s[16];
            #pragma unroll
            for (int k = 0; k < 16; ++k) {
                unsigned int v = H[k * 64 + ln];
                #pragma unroll
                for (int off = 1; off < 64; off <<= 1) {
                    unsigned int o = __shfl_down(v, off, 64);
                    if (ln + off < 64) v += o;
                }
                s[k] = v;
            }
            unsigned int after = 0;
            #pragma unroll
            for (int k = 15; k >= 0; --k) {
                unsigned int tot = __shfl(s[k], 0, 64);
                H[k * 64 + ln] = s[k] + after;
                after += tot;
            }
        }
    }
    __syncthreads();
    const unsigned int nneg = hist[0];
    const unsigned int npos = hist2[0];

    // ---- kth = 128th-largest pos noise (capacity-free, exact) --------------
    if (npos >= MAX_FG) {                       // block-uniform branch
        {   // boundary bucket: suffix2(Bp) >= 128 > suffix2(Bp+1); unique writer
            unsigned int S  = hist2[tid];
            unsigned int Sn = (tid < 1023) ? hist2[tid + 1] : 0;
            if (S >= MAX_FG && Sn < MAX_FG) { sh_Bp = tid; sh_needp = MAX_FG - Sn; }
        }
        __syncthreads();
        const unsigned int Bp = sh_Bp, needp = sh_needp;
        // collect pos members of bucket Bp (~npos/1024 of them) — from regs
        #pragma unroll
        for (int k = 0; k < 8; ++k) {
            if (((pb >> k) & 1u) && bkt1024(f[k]) == Bp) {
                unsigned int slot = atomicAdd(&sh_cc, 1u);
                if (slot < C_CAP) C[slot] = f[k];
            }
        }
        if (tid < 16) {
            unsigned int pb2 = posmask[1024 + tid];
            #pragma unroll
            for (int k = 0; k < 8; ++k) {
                if ((pb2 >> k) & 1u) {
                    float v = sh_ns[(1024 + tid) * 8 + k];
                    if (bkt1024(v) == Bp) {
                        unsigned int slot = atomicAdd(&sh_cc, 1u);
                        if (slot < C_CAP) C[slot] = v;
                    }
                }
            }
        }
        __syncthreads();
        {   // exact in-bucket value rank: v with #greater < needp <= #greater+#eq
            unsigned int cc = min(sh_cc, (unsigned int)C_CAP);
            if (tid < (int)cc) {
                float my = C[tid];
                unsigned int g = 0, e = 0;
                for (unsigned int j = 0; j < cc; ++j) {
                    float v = C[j];
                    g += (v > my) ? 1u : 0u;
                    e += (v == my) ? 1u : 0u;
                }
                if (g < needp && g + e >= needp) sh_kth = __float_as_uint(my);
            }
        }
        __syncthreads();
    }
    const float kthf = __uint_as_float(sh_kth);

    // ---- selp collection: pos && ns >= kth (<= ~130 members) — from regs ---
    #pragma unroll
    for (int k = 0; k < 8; ++k) {
        if (((pb >> k) & 1u) && f[k] >= kthf) {
            unsigned int slot = atomicAdd(&sh_n1a, 1u);
            if (slot < S_CAP) slist[slot] = (unsigned short)(tid * 8 + k);
        }
    }
    if (tid < 16) {
        unsigned int pb2 = posmask[1024 + tid];
        #pragma unroll
        for (int k = 0; k < 8; ++k) {
            if ((pb2 >> k) & 1u) {
                int m = (1024 + tid) * 8 + k;
                if (sh_ns[m] >= kthf) {
                    unsigned int slot = atomicAdd(&sh_n1a, 1u);
                    if (slot < S_CAP) slist[slot] = (unsigned short)m;
                }
            }
        }
    }
    __syncthreads();
    const unsigned int n1 = min(sh_n1a, (unsigned int)S_CAP);
    const unsigned int k2 = K_OUT - n1;         // >= 382
    const bool enough_neg = (nneg >= k2);

    // ---- selp rank/write + neg boundary (same phase, then barrier) ---------
    if (enough_neg) {
        unsigned int S  = hist[tid];
        unsigned int Sn = (tid < 1023) ? hist[tid + 1] : 0;
        if (S >= k2 && Sn < k2) sh_B = tid;     // unique writer
    }   // else sh_B stays 0 -> union = all negs
    if (tid < (int)n1) {
        int mi = slist[tid];
        float nsi = sh_ns[mi];
        float ci = __fadd_rn(2.0f, nsi);
        unsigned int r = 0;
        for (unsigned int j = 0; j < n1; ++j) {
            int mj = slist[j];
            float cj = __fadd_rn(2.0f, sh_ns[mj]);
            if (cj > ci || (cj == ci && mj < mi)) ++r;
        }
        int pkv = packed[(size_t)b * M + mi];
        int lbl = pkv & 127;
        float4 roi = (mi < NBOX) ? ((const float4*)boxes)[b * NBOX + mi]
                                 : sgt[mi - NBOX];
        ((float4*)out_bt)[b * K_OUT + r] = sgt[lbl];
        out_cls[b * K_OUT + r] = (float)slab[lbl];
        ((float4*)out_roi)[b * K_OUT + r] = roi;
        out_p2l[b * K_OUT + r] = (float)lbl;
    }
    __syncthreads();
    const unsigned int B1 = sh_B;

    // ---- compact neg union (buckets >= B1) — regs + ballot aggregation -----
    #pragma unroll
    for (int k = 0; k < 8; ++k) {
        float v = f[k];
        bool p = ((nb >> k) & 1u) && bkt1024(v) >= B1;
        unsigned short mm = (unsigned short)(tid * 8 + k);
        wave_compact(p, &sh_cnt, U_CAP, [&](unsigned int s) {
            ukey[s] = __float_as_uint(v);      // v >= 0: uint-monotone
            um[s]   = mm;
        });
    }
    {   // tail chunks (only wave 0 has candidates; other waves fall through)
        unsigned int nb2 = (tid < 16) ? (unsigned int)negmask[1024 + tid] : 0u;
        #pragma unroll
        for (int k = 0; k < 8; ++k) {
            bool p = (nb2 >> k) & 1u;
            float v = p ? sh_ns[(1024 + tid) * 8 + k] : 0.0f;
            p = p && bkt1024(v) >= B1;
            unsigned short mm = (unsigned short)((1024 + tid) * 8 + k);
            wave_compact(p, &sh_cnt, U_CAP, [&](unsigned int s) {
                ukey[s] = __float_as_uint(v);
                um[s]   = mm;
            });
        }
    }
    __syncthreads();

    // ---- exact pairwise rank of union; write neg outputs -------------------
    const unsigned int q = min(sh_cnt, (unsigned int)U_CAP);
    if (tid < 4) { ukey[q + tid] = 0u; um[q + tid] = 0xFFFFu; }  // pad: never counts
    __syncthreads();
    for (unsigned int i = tid; i < q; i += 1024) {
        unsigned int ki = ukey[i];
        unsigned short mi = um[i];
        unsigned int r = 0;
        for (unsigned int j = 0; j < q; j += 4) {
            uint4 kv = *(const uint4*)&ukey[j];
            ushort4 mv = *(const ushort4*)&um[j];
            r += (kv.x > ki || (kv.x == ki && mv.x < mi)) ? 1u : 0u;
            r += (kv.y > ki || (kv.y == ki && mv.y < mi)) ? 1u : 0u;
            r += (kv.z > ki || (kv.z == ki && mv.z < mi)) ? 1u : 0u;
            r += (kv.w > ki || (kv.w == ki && mv.w < mi)) ? 1u : 0u;
        }
        if (r < k2) {
            float4 roi = (mi < NBOX) ? ((const float4*)boxes)[b * NBOX + mi]
                                     : sgt[mi - NBOX];
            unsigned int gr = n1 + r;
            ((float4*)out_bt)[b * K_OUT + gr] = make_float4(0.f, 0.f, 0.f, 0.f);
            out_cls[b * K_OUT + gr] = 0.0f;
            ((float4*)out_roi)[b * K_OUT + gr] = roi;
            out_p2l[b * K_OUT + gr] = 0.0f;
        }
    }

    // ---- fallback (statistically impossible: nneg < k2): rest by m asc -----
    if (!enough_neg) {
        __syncthreads();
        const unsigned int k3 = k2 - nneg;
        for (int m = tid; m < M; m += 1024) {
            if (((posmask[m >> 3] >> (m & 7)) & 1) && sh_ns[m] < kthf) {
                unsigned int r = 0;
                for (int m2 = 0; m2 < m; ++m2)
                    if (((posmask[m2 >> 3] >> (m2 & 7)) & 1) && sh_ns[m2] < kthf) ++r;
                if (r < k3) {
                    int pkv = packed[(size_t)b * M + m];
                    int lbl = pkv & 127;
                    float4 roi = (m < NBOX) ? ((const float4*)boxes)[b * NBOX + m]
                                            : sgt[m - NBOX];
                    unsigned int gr = n1 + nneg + r;
                    ((float4*)out_bt)[b * K_OUT + gr] = sgt[lbl];
                    out_cls[b * K_OUT + gr] = (float)slab[lbl];
                    ((float4*)out_roi)[b * K_OUT + gr] = roi;
                    out_p2l[b * K_OUT + gr] = (float)lbl;
                }
            }
        }
    }
}

extern "C" void kernel_launch(void* const* d_in, const int* in_sizes, int n_in,
                              void* d_out, int out_size, void* d_ws, size_t ws_size,
                              hipStream_t stream) {
    const float* boxes     = (const float*)d_in[0];
    const float* gt_boxes  = (const float*)d_in[1];
    const int*   gt_labels = (const int*)d_in[2];
    const float* noise     = (const float*)d_in[3];
    unsigned short* packed = (unsigned short*)d_ws;   // B*M u16 = 532,480 B
    float* out = (float*)d_out;

    iou_kernel<<<BATCH * 65, 128, 0, stream>>>(boxes, gt_boxes, packed);
    select_kernel<<<BATCH, 1024, 0, stream>>>(boxes, gt_boxes, gt_labels, noise,
                                              packed, out);
}

// Round 3
// 115.858 us; speedup vs baseline: 1.0449x; 1.0449x over previous
//
#include <hip/hip_runtime.h>
#include <stdint.h>

#define BATCH 32
#define NBOX 8192
#define NGT 128
#define M (NBOX + NGT)     // 8320
#define K_OUT 512
#define MAX_FG 128
#define C_CAP 256          // kth boundary-bucket members (~npos/1024, Poisson)
#define S_CAP 256          // selp members (<= 128 + value-ties)
#define U_CAP 1024         // neg union (<= k2 + boundary bucket)

#define IOU_TPB 256
#define IOU_VPT 2
#define IOU_SPAN (IOU_TPB * IOU_VPT)              // 512
#define IOU_BPB ((M + IOU_SPAN - 1) / IOU_SPAN)   // 17

// Monotone clamped bucket: v1>v2 => bkt(v1)>=bkt(v2); bkt(v1)>bkt(v2) => v1>v2.
// Equal floats => equal bucket. Clamp handles ns ~ 1-eps.
__device__ __forceinline__ unsigned int bkt1024(float ns) {
    unsigned int u = (unsigned int)(ns * 16777216.0f) >> 14;
    return u > 1023u ? 1023u : u;
}

// ---------------------------------------------------------------------------
// Kernel 1 v3: 2 boxes/thread (ILP-2 div chains), gt + areas staged in LDS
// (broadcast ds_reads, conflict-free; off the VALU path). Exact __f*_rn
// arithmetic, exact __fdiv_rn ordering (rounded-quotient ties -> first index
// is semantically observable; verified absmax 0.0 previously).
// ---------------------------------------------------------------------------
__global__ __launch_bounds__(256) void iou_kernel(
    const float* __restrict__ boxes,      // [B, NBOX, 4]
    const float* __restrict__ gt_boxes,   // [B, NGT, 4]
    unsigned short* __restrict__ packed)  // [B, M]
{
    const int b   = blockIdx.x / IOU_BPB;
    const int blk = blockIdx.x % IOU_BPB;
    const int t   = threadIdx.x;

    __shared__ float4 sgt[NGT];
    __shared__ float  sga[NGT];
    if (t < NGT) {
        float4 g = ((const float4*)gt_boxes)[b * NGT + t];
        sgt[t] = g;
        sga[t] = __fmul_rn(__fsub_rn(g.z, g.x), __fsub_rn(g.w, g.y));
    }
    __syncthreads();

    const int m0 = blk * IOU_SPAN + t;
    const int m1 = m0 + IOU_TPB;
    const bool v0 = m0 < M, v1 = m1 < M;

    float4 bb0 = make_float4(0.f, 0.f, 1.f, 1.f);
    float4 bb1 = make_float4(0.f, 0.f, 1.f, 1.f);
    if (v0) bb0 = (m0 < NBOX) ? ((const float4*)boxes)[b * NBOX + m0] : sgt[m0 - NBOX];
    if (v1) bb1 = (m1 < NBOX) ? ((const float4*)boxes)[b * NBOX + m1] : sgt[m1 - NBOX];
    float a0 = __fmul_rn(__fsub_rn(bb0.z, bb0.x), __fsub_rn(bb0.w, bb0.y));
    float a1 = __fmul_rn(__fsub_rn(bb1.z, bb1.x), __fsub_rn(bb1.w, bb1.y));

    float best0 = -1e30f, best1 = -1e30f;
    int i0 = 0, i1 = 0;
    #pragma unroll 4
    for (int g = 0; g < NGT; ++g) {
        float4 gg = sgt[g];
        float  ga = sga[g];
        {
            float iymin = fmaxf(bb0.x, gg.x);
            float ixmin = fmaxf(bb0.y, gg.y);
            float iymax = fminf(bb0.z, gg.z);
            float ixmax = fminf(bb0.w, gg.w);
            float ia  = __fmul_rn(fmaxf(__fsub_rn(iymax, iymin), 0.0f),
                                  fmaxf(__fsub_rn(ixmax, ixmin), 0.0f));
            float den = __fsub_rn(__fadd_rn(a0, ga), ia);
            float iou = __fdiv_rn(ia, den);
            if (iou > best0) { best0 = iou; i0 = g; }    // first-max = argmax
        }
        {
            float iymin = fmaxf(bb1.x, gg.x);
            float ixmin = fmaxf(bb1.y, gg.y);
            float iymax = fminf(bb1.z, gg.z);
            float ixmax = fminf(bb1.w, gg.w);
            float ia  = __fmul_rn(fmaxf(__fsub_rn(iymax, iymin), 0.0f),
                                  fmaxf(__fsub_rn(ixmax, ixmin), 0.0f));
            float den = __fsub_rn(__fadd_rn(a1, ga), ia);
            float iou = __fdiv_rn(ia, den);
            if (iou > best1) { best1 = iou; i1 = g; }
        }
    }
    if (v0) {
        bool pos = best0 > 0.5f;
        bool neg = (best0 >= 0.0f) && (best0 < 0.5f);
        packed[b * M + m0] = (unsigned short)(i0 | (neg ? 256 : 0) | (pos ? 512 : 0));
    }
    if (v1) {
        bool pos = best1 > 0.5f;
        bool neg = (best1 >= 0.0f) && (best1 < 0.5f);
        packed[b * M + m1] = (unsigned short)(i1 | (neg ? 256 : 0) | (pos ? 512 : 0));
    }
}

// ---------------------------------------------------------------------------
// Kernel 2 v3: one block (1024 thr) per batch.
// - load pass: regs f[8] + masks + two 1024-bin histograms (unchanged, verified)
// - kth via boundary bucket + exact value-rank (unchanged)
// - selp: compact (key=RN(2+ns) bits, idx) list; exact pairwise rank with
//   vectorized uint4/ushort4 LDS reads (n1 <= ~130)
// - negs: histogram-exact bucket placement. Suffix counts give each bucket's
//   exact output-rank base; members placed positionally into per-bucket
//   segments; within-bucket rank by exact (value, idx) over ~4-8 members.
//   Rank-exact vs full sort: bkt strictly monotone, equal values share bucket.
// ---------------------------------------------------------------------------
__global__ __launch_bounds__(1024) void select_kernel(
    const float* __restrict__ boxes,
    const float* __restrict__ gt_boxes,
    const int*   __restrict__ gt_labels,
    const float* __restrict__ noise,      // [B, M]
    const unsigned short* __restrict__ packed,
    float* __restrict__ out)
{
    const int b = blockIdx.x;
    const int tid = threadIdx.x;

    __shared__ float sh_ns[M];                 // 33280 B
    __shared__ unsigned int hist[1024];        // neg hist -> suffix counts
    __shared__ unsigned int hist2[1024];       // pos hist -> suffix counts
    __shared__ unsigned int bctr[1024];        // per-bucket placement counters
    __shared__ unsigned char posmask[M / 8];
    __shared__ unsigned char negmask[M / 8];
    __shared__ float4 sgt[NGT];
    __shared__ int slab[NGT];
    __shared__ float C[C_CAP];
    __shared__ __align__(16) unsigned int   skey[S_CAP + 4];
    __shared__ __align__(16) unsigned short sm[S_CAP + 4];
    __shared__ unsigned int   ukey[U_CAP];
    __shared__ unsigned short um[U_CAP];
    __shared__ unsigned int sh_Bp, sh_needp, sh_cc, sh_n1a, sh_B, sh_kth;

    float* out_bt  = out;
    float* out_cls = out + BATCH * K_OUT * 4;
    float* out_roi = out + BATCH * K_OUT * 5;
    float* out_p2l = out + BATCH * K_OUT * 9;

    // ---- init + stage gt ---------------------------------------------------
    hist[tid] = 0;
    hist2[tid] = 0;
    bctr[tid] = 0;
    if (tid == 0) { sh_cc = 0; sh_n1a = 0; sh_B = 0; sh_kth = 0xBF800000u; }
    if (tid < NGT) {
        sgt[tid]  = ((const float4*)gt_boxes)[b * NGT + tid];
        slab[tid] = gt_labels[b * NGT + tid];
    }
    __syncthreads();

    // ---- load pass: noise -> LDS + regs, masks + two histograms ------------
    float f[8];                                // this thread's chunk (c = tid)
    unsigned int pb = 0, nb = 0;
    {
        const uint4*  pk4 = (const uint4*)(packed + (size_t)b * M);  // 8 u16/load
        const float4* ns4 = (const float4*)(noise + (size_t)b * M);
        {
            uint4 pv = pk4[tid];
            float4 n0 = ns4[2 * tid], n1v = ns4[2 * tid + 1];
            ((float4*)sh_ns)[2 * tid] = n0;
            ((float4*)sh_ns)[2 * tid + 1] = n1v;
            f[0] = n0.x; f[1] = n0.y; f[2] = n0.z; f[3] = n0.w;
            f[4] = n1v.x; f[5] = n1v.y; f[6] = n1v.z; f[7] = n1v.w;
            unsigned short e[8];
            e[0] = (unsigned short)(pv.x & 0xFFFF); e[1] = (unsigned short)(pv.x >> 16);
            e[2] = (unsigned short)(pv.y & 0xFFFF); e[3] = (unsigned short)(pv.y >> 16);
            e[4] = (unsigned short)(pv.z & 0xFFFF); e[5] = (unsigned short)(pv.z >> 16);
            e[6] = (unsigned short)(pv.w & 0xFFFF); e[7] = (unsigned short)(pv.w >> 16);
            #pragma unroll
            for (int k = 0; k < 8; ++k) {
                if (e[k] & 512) {
                    pb |= (1u << k);
                    atomicAdd(&hist2[bkt1024(f[k])], 1u);
                } else if (e[k] & 256) {
                    nb |= (1u << k);
                    atomicAdd(&hist[bkt1024(f[k])], 1u);
                }
            }
            posmask[tid] = (unsigned char)pb;
            negmask[tid] = (unsigned char)nb;
        }
        if (tid < 16) {                        // tail chunks 1024..1039
            int c = 1024 + tid;
            uint4 pv = pk4[c];
            float4 n0 = ns4[2 * c], n1v = ns4[2 * c + 1];
            ((float4*)sh_ns)[2 * c] = n0;
            ((float4*)sh_ns)[2 * c + 1] = n1v;
            float ft[8] = {n0.x, n0.y, n0.z, n0.w, n1v.x, n1v.y, n1v.z, n1v.w};
            unsigned short e[8];
            e[0] = (unsigned short)(pv.x & 0xFFFF); e[1] = (unsigned short)(pv.x >> 16);
            e[2] = (unsigned short)(pv.y & 0xFFFF); e[3] = (unsigned short)(pv.y >> 16);
            e[4] = (unsigned short)(pv.z & 0xFFFF); e[5] = (unsigned short)(pv.z >> 16);
            e[6] = (unsigned short)(pv.w & 0xFFFF); e[7] = (unsigned short)(pv.w >> 16);
            unsigned int pb2 = 0, nb2 = 0;
            #pragma unroll
            for (int k = 0; k < 8; ++k) {
                if (e[k] & 512) {
                    pb2 |= (1u << k);
                    atomicAdd(&hist2[bkt1024(ft[k])], 1u);
                } else if (e[k] & 256) {
                    nb2 |= (1u << k);
                    atomicAdd(&hist[bkt1024(ft[k])], 1u);
                }
            }
            posmask[c] = (unsigned char)pb2;
            negmask[c] = (unsigned char)nb2;
        }
    }
    __syncthreads();

    // ---- suffix scans: wave 0 -> hist (neg), wave 1 -> hist2 (pos) ---------
    {
        const int wv = tid >> 6, ln = tid & 63;
        if (wv < 2) {
            unsigned int* H = wv ? hist2 : hist;
            unsigned int s[16];
            #pragma unroll
            for (int k = 0; k < 16; ++k) {
                unsigned int v = H[k * 64 + ln];
                #pragma unroll
                for (int off = 1; off < 64; off <<= 1) {
                    unsigned int o = __shfl_down(v, off, 64);
                    if (ln + off < 64) v += o;
                }
                s[k] = v;
            }
            unsigned int after = 0;
            #pragma unroll
            for (int k = 15; k >= 0; --k) {
                unsigned int tot = __shfl(s[k], 0, 64);
                H[k * 64 + ln] = s[k] + after;
                after += tot;
            }
        }
    }
    __syncthreads();
    const unsigned int nneg = hist[0];
    const unsigned int npos = hist2[0];

    // ---- kth = 128th-largest pos noise (capacity-free, exact) --------------
    if (npos >= MAX_FG) {                       // block-uniform branch
        {
            unsigned int S  = hist2[tid];
            unsigned int Sn = (tid < 1023) ? hist2[tid + 1] : 0;
            if (S >= MAX_FG && Sn < MAX_FG) { sh_Bp = tid; sh_needp = MAX_FG - Sn; }
        }
        __syncthreads();
        const unsigned int Bp = sh_Bp, needp = sh_needp;
        #pragma unroll
        for (int k = 0; k < 8; ++k) {
            if (((pb >> k) & 1u) && bkt1024(f[k]) == Bp) {
                unsigned int slot = atomicAdd(&sh_cc, 1u);
                if (slot < C_CAP) C[slot] = f[k];
            }
        }
        if (tid < 16) {
            unsigned int pb2 = posmask[1024 + tid];
            #pragma unroll
            for (int k = 0; k < 8; ++k) {
                if ((pb2 >> k) & 1u) {
                    float v = sh_ns[(1024 + tid) * 8 + k];
                    if (bkt1024(v) == Bp) {
                        unsigned int slot = atomicAdd(&sh_cc, 1u);
                        if (slot < C_CAP) C[slot] = v;
                    }
                }
            }
        }
        __syncthreads();
        {   // exact in-bucket value rank: v with #greater < needp <= #greater+#eq
            unsigned int cc = min(sh_cc, (unsigned int)C_CAP);
            if (tid < (int)cc) {
                float my = C[tid];
                unsigned int g = 0, e = 0;
                for (unsigned int j = 0; j < cc; ++j) {
                    float v = C[j];
                    g += (v > my) ? 1u : 0u;
                    e += (v == my) ? 1u : 0u;
                }
                if (g < needp && g + e >= needp) sh_kth = __float_as_uint(my);
            }
        }
        __syncthreads();
    }
    const float kthf = __uint_as_float(sh_kth);

    // ---- selp collection: pos && ns >= kth; store key = bits(2+ns) ---------
    #pragma unroll
    for (int k = 0; k < 8; ++k) {
        if (((pb >> k) & 1u) && f[k] >= kthf) {
            unsigned int slot = atomicAdd(&sh_n1a, 1u);
            if (slot < S_CAP) {
                skey[slot] = __float_as_uint(__fadd_rn(2.0f, f[k]));
                sm[slot]   = (unsigned short)(tid * 8 + k);
            }
        }
    }
    if (tid < 16) {
        unsigned int pb2 = posmask[1024 + tid];
        #pragma unroll
        for (int k = 0; k < 8; ++k) {
            if ((pb2 >> k) & 1u) {
                int m = (1024 + tid) * 8 + k;
                float v = sh_ns[m];
                if (v >= kthf) {
                    unsigned int slot = atomicAdd(&sh_n1a, 1u);
                    if (slot < S_CAP) {
                        skey[slot] = __float_as_uint(__fadd_rn(2.0f, v));
                        sm[slot]   = (unsigned short)m;
                    }
                }
            }
        }
    }
    __syncthreads();
    const unsigned int n1 = min(sh_n1a, (unsigned int)S_CAP);
    const unsigned int k2 = K_OUT - n1;         // >= 382 expected
    const bool enough_neg = (nneg >= k2);

    if (tid < 4) { skey[n1 + tid] = 0u; sm[n1 + tid] = 0xFFFFu; }  // pad: never counts
    if (enough_neg) {
        unsigned int S  = hist[tid];
        unsigned int Sn = (tid < 1023) ? hist[tid + 1] : 0;
        if (S >= k2 && Sn < k2) sh_B = tid;     // unique writer
    }   // else sh_B stays 0 -> place all negs
    __syncthreads();
    const unsigned int B1 = sh_B;

    // ---- selp exact pairwise rank (vectorized LDS reads) + fg writes -------
    if (tid < (int)n1) {
        unsigned int   ki = skey[tid];
        unsigned short mi = sm[tid];
        unsigned int r = 0;
        for (unsigned int j = 0; j < n1; j += 4) {
            uint4   kv = *(const uint4*)&skey[j];
            ushort4 mv = *(const ushort4*)&sm[j];
            r += (kv.x > ki || (kv.x == ki && mv.x < mi)) ? 1u : 0u;
            r += (kv.y > ki || (kv.y == ki && mv.y < mi)) ? 1u : 0u;
            r += (kv.z > ki || (kv.z == ki && mv.z < mi)) ? 1u : 0u;
            r += (kv.w > ki || (kv.w == ki && mv.w < mi)) ? 1u : 0u;
        }
        int mi_ = mi;
        int pkv = packed[(size_t)b * M + mi_];
        int lbl = pkv & 127;
        float4 roi = (mi_ < NBOX) ? ((const float4*)boxes)[b * NBOX + mi_]
                                  : sgt[mi_ - NBOX];
        ((float4*)out_bt)[b * K_OUT + r] = sgt[lbl];
        out_cls[b * K_OUT + r] = (float)slab[lbl];
        ((float4*)out_roi)[b * K_OUT + r] = roi;
        out_p2l[b * K_OUT + r] = (float)lbl;
    }

    // ---- neg bucket placement: positional, rank-exact ----------------------
    // Member of bucket be lands in segment [base(be), hist[be]) where
    // base(be) = hist[be+1] (suffix counts). Segments partition [0, hist[B1]).
    #pragma unroll
    for (int k = 0; k < 8; ++k) {
        if ((nb >> k) & 1u) {
            float v = f[k];
            unsigned int be = bkt1024(v);
            if (be >= B1) {
                unsigned int base = (be < 1023) ? hist[be + 1] : 0;
                unsigned int a = base + atomicAdd(&bctr[be], 1u);
                if (a < U_CAP) {
                    ukey[a] = __float_as_uint(v);   // v >= 0: uint-monotone
                    um[a]   = (unsigned short)(tid * 8 + k);
                }
            }
        }
    }
    if (tid < 16) {
        unsigned int nb2 = negmask[1024 + tid];
        #pragma unroll
        for (int k = 0; k < 8; ++k) {
            if ((nb2 >> k) & 1u) {
                int m = (1024 + tid) * 8 + k;
                float v = sh_ns[m];
                unsigned int be = bkt1024(v);
                if (be >= B1) {
                    unsigned int base = (be < 1023) ? hist[be + 1] : 0;
                    unsigned int a = base + atomicAdd(&bctr[be], 1u);
                    if (a < U_CAP) {
                        ukey[a] = __float_as_uint(v);
                        um[a]   = (unsigned short)m;
                    }
                }
            }
        }
    }
    __syncthreads();

    // ---- neg finalize: within-bucket exact rank over own segment -----------
    const unsigned int q = min(hist[B1], (unsigned int)U_CAP);
    for (unsigned int a = tid; a < q; a += 1024) {
        unsigned int   ki = ukey[a];
        unsigned short mi = um[a];
        unsigned int be = bkt1024(__uint_as_float(ki));
        unsigned int base = (be < 1023) ? hist[be + 1] : 0;
        unsigned int end  = min(hist[be], q);
        unsigned int r = base;
        for (unsigned int j = base; j < end; ++j) {
            unsigned int kj = ukey[j];
            if (kj > ki || (kj == ki && um[j] < mi)) ++r;
        }
        if (r < k2) {
            float4 roi = (mi < NBOX) ? ((const float4*)boxes)[b * NBOX + mi]
                                     : sgt[mi - NBOX];
            unsigned int gr = n1 + r;
            ((float4*)out_bt)[b * K_OUT + gr] = make_float4(0.f, 0.f, 0.f, 0.f);
            out_cls[b * K_OUT + gr] = 0.0f;
            ((float4*)out_roi)[b * K_OUT + gr] = roi;
            out_p2l[b * K_OUT + gr] = 0.0f;
        }
    }

    // ---- fallback (statistically impossible: nneg < k2): rest by m asc -----
    if (!enough_neg) {
        __syncthreads();
        const unsigned int k3 = k2 - nneg;
        for (int m = tid; m < M; m += 1024) {
            if (((posmask[m >> 3] >> (m & 7)) & 1) && sh_ns[m] < kthf) {
                unsigned int r = 0;
                for (int m2 = 0; m2 < m; ++m2)
                    if (((posmask[m2 >> 3] >> (m2 & 7)) & 1) && sh_ns[m2] < kthf) ++r;
                if (r < k3) {
                    int pkv = packed[(size_t)b * M + m];
                    int lbl = pkv & 127;
                    float4 roi = (m < NBOX) ? ((const float4*)boxes)[b * NBOX + m]
                                            : sgt[m - NBOX];
                    unsigned int gr = n1 + nneg + r;
                    ((float4*)out_bt)[b * K_OUT + gr] = sgt[lbl];
                    out_cls[b * K_OUT + gr] = (float)slab[lbl];
                    ((float4*)out_roi)[b * K_OUT + gr] = roi;
                    out_p2l[b * K_OUT + gr] = (float)lbl;
                }
            }
        }
    }
}

extern "C" void kernel_launch(void* const* d_in, const int* in_sizes, int n_in,
                              void* d_out, int out_size, void* d_ws, size_t ws_size,
                              hipStream_t stream) {
    const float* boxes     = (const float*)d_in[0];
    const float* gt_boxes  = (const float*)d_in[1];
    const int*   gt_labels = (const int*)d_in[2];
    const float* noise     = (const float*)d_in[3];
    unsigned short* packed = (unsigned short*)d_ws;   // B*M u16 = 532,480 B
    float* out = (float*)d_out;

    iou_kernel<<<BATCH * IOU_BPB, IOU_TPB, 0, stream>>>(boxes, gt_boxes, packed);
    select_kernel<<<BATCH, 1024, 0, stream>>>(boxes, gt_boxes, gt_labels, noise,
                                              packed, out);
}

// Round 4
// 107.190 us; speedup vs baseline: 1.1295x; 1.0809x over previous
//
#include <hip/hip_runtime.h>
#include <stdint.h>

#define BATCH 32
#define NBOX 8192
#define NGT 128
#define M (NBOX + NGT)     // 8320
#define K_OUT 512
#define MAX_FG 128
#define C_CAP 256          // kth boundary-bucket members (~npos/1024, Poisson)
#define S_CAP 256          // selp members (<= 128 + value-ties)
#define U_CAP 1024         // neg union (<= k2 + boundary bucket)

#define GSPLIT 2
#define GPER (NGT / GSPLIT)                       // 64 gts per split
#define IOU_TPB 256
#define IOU_CB ((M + IOU_TPB - 1) / IOU_TPB)      // 33 box-chunks

// Monotone clamped bucket: v1>v2 => bkt(v1)>=bkt(v2); bkt(v1)>bkt(v2) => v1>v2.
__device__ __forceinline__ unsigned int bkt1024(float ns) {
    unsigned int u = (unsigned int)(ns * 16777216.0f) >> 14;
    return u > 1023u ? 1023u : u;
}

#define U64KEY(lo, hi) (((unsigned long long)(hi) << 32) | (unsigned long long)(lo))

// ---------------------------------------------------------------------------
// Kernel 1 v4: gt-SPLIT for occupancy. Each block: 256 boxes x 64 gts
// (partial max). Grid 32*33*2 = 2112 blocks = 33 waves/CU (vs 8.5 in v3) --
// the latency-bound div chain now hides behind 8 waves/SIMD of TLP.
// Partial result is an order-exact u64 key: (bits(best)<<32) | (127-idx).
// best >= 0 always (iou >= 0), so bits are uint-monotone; tie -> larger
// (127-idx) -> smaller idx = first-max. max(key_s0, key_s1) = global
// first-max argmax. Exact __f*_rn / __fdiv_rn arithmetic unchanged.
// ---------------------------------------------------------------------------
__global__ __launch_bounds__(256) void iou_kernel(
    const float* __restrict__ boxes,      // [B, NBOX, 4]
    const float* __restrict__ gt_boxes,   // [B, NGT, 4]
    unsigned long long* __restrict__ part) // [GSPLIT, B, M]
{
    const int s  = blockIdx.x % GSPLIT;
    const int cb = (blockIdx.x / GSPLIT) % IOU_CB;
    const int b  = blockIdx.x / (GSPLIT * IOU_CB);
    const int t  = threadIdx.x;
    const int g0 = s * GPER;

    __shared__ float4 sgt[GPER];
    __shared__ float  sga[GPER];
    if (t < GPER) {
        float4 g = ((const float4*)gt_boxes)[b * NGT + g0 + t];
        sgt[t] = g;
        sga[t] = __fmul_rn(__fsub_rn(g.z, g.x), __fsub_rn(g.w, g.y));
    }
    __syncthreads();

    const int m = cb * IOU_TPB + t;
    if (m >= M) return;

    float4 bb = (m < NBOX) ? ((const float4*)boxes)[b * NBOX + m]
                           : ((const float4*)gt_boxes)[b * NGT + (m - NBOX)];
    float ba = __fmul_rn(__fsub_rn(bb.z, bb.x), __fsub_rn(bb.w, bb.y));

    float best = -1e30f;
    int bi = 0;
    #pragma unroll 4
    for (int g = 0; g < GPER; ++g) {
        float4 gg = sgt[g];
        float iymin = fmaxf(bb.x, gg.x);
        float ixmin = fmaxf(bb.y, gg.y);
        float iymax = fminf(bb.z, gg.z);
        float ixmax = fminf(bb.w, gg.w);
        float ia  = __fmul_rn(fmaxf(__fsub_rn(iymax, iymin), 0.0f),
                              fmaxf(__fsub_rn(ixmax, ixmin), 0.0f));
        float den = __fsub_rn(__fadd_rn(ba, sga[g]), ia);
        float iou = __fdiv_rn(ia, den);
        if (iou > best) { best = iou; bi = g0 + g; }     // first-max = argmax
    }
    // best >= 0 here (first iteration always beats -1e30; iou >= 0).
    part[((size_t)s * BATCH + b) * M + m] =
        U64KEY(127u - (unsigned int)bi, __float_as_uint(best));
}

// ---------------------------------------------------------------------------
// Kernel 2 v4: one block (1024 thr) per batch.
// Load pass merges the GSPLIT partial u64 keys (max = exact global argmax),
// decodes pos/neg from the key's value bits (best>0.5 <=> bits>0x3F000000;
// best<0.5 <=> bits<0x3F000000; best>=0 always), stores argmax idx in LDS
// byte array (replaces later global packed re-reads). Everything downstream
// (histograms, boundary-bucket kth, selp pairwise rank, neg positional
// bucket placement + within-bucket exact rank) unchanged from verified v3.
// ---------------------------------------------------------------------------
__global__ __launch_bounds__(1024) void select_kernel(
    const float* __restrict__ boxes,
    const float* __restrict__ gt_boxes,
    const int*   __restrict__ gt_labels,
    const float* __restrict__ noise,      // [B, M]
    const unsigned long long* __restrict__ part,  // [GSPLIT, B, M]
    float* __restrict__ out)
{
    const int b = blockIdx.x;
    const int tid = threadIdx.x;

    __shared__ float sh_ns[M];                 // 33280 B
    __shared__ unsigned char sh_idx[M];        // 8320 B (argmax per item)
    __shared__ unsigned int hist[1024];        // neg hist -> suffix counts
    __shared__ unsigned int hist2[1024];       // pos hist -> suffix counts
    __shared__ unsigned int bctr[1024];        // per-bucket placement counters
    __shared__ unsigned char posmask[M / 8];
    __shared__ unsigned char negmask[M / 8];
    __shared__ float4 sgt[NGT];
    __shared__ int slab[NGT];
    __shared__ float C[C_CAP];
    __shared__ __align__(16) unsigned int   skey[S_CAP + 4];
    __shared__ __align__(16) unsigned short sm[S_CAP + 4];
    __shared__ unsigned int   ukey[U_CAP];
    __shared__ unsigned short um[U_CAP];
    __shared__ unsigned int sh_Bp, sh_needp, sh_cc, sh_n1a, sh_B, sh_kth;

    float* out_bt  = out;
    float* out_cls = out + BATCH * K_OUT * 4;
    float* out_roi = out + BATCH * K_OUT * 5;
    float* out_p2l = out + BATCH * K_OUT * 9;

    // ---- init + stage gt ---------------------------------------------------
    hist[tid] = 0;
    hist2[tid] = 0;
    bctr[tid] = 0;
    if (tid == 0) { sh_cc = 0; sh_n1a = 0; sh_B = 0; sh_kth = 0xBF800000u; }
    if (tid < NGT) {
        sgt[tid]  = ((const float4*)gt_boxes)[b * NGT + tid];
        slab[tid] = gt_labels[b * NGT + tid];
    }
    __syncthreads();

    // ---- load pass: merge split keys, noise -> LDS + regs, masks + hists ---
    float f[8];                                // this thread's chunk (c = tid)
    unsigned int pb = 0, nb = 0;
    {
        const unsigned long long* P0 = part + ((size_t)0 * BATCH + b) * M;
        const unsigned long long* P1 = part + ((size_t)1 * BATCH + b) * M;
        const float4* ns4 = (const float4*)(noise + (size_t)b * M);
        {
            const int c = tid;
            const uint4* a4 = (const uint4*)(P0 + (size_t)c * 8);
            const uint4* b4 = (const uint4*)(P1 + (size_t)c * 8);
            uint4 A0 = a4[0], A1 = a4[1], A2 = a4[2], A3 = a4[3];
            uint4 B0 = b4[0], B1 = b4[1], B2 = b4[2], B3 = b4[3];
            float4 n0 = ns4[2 * c], n1v = ns4[2 * c + 1];
            ((float4*)sh_ns)[2 * c] = n0;
            ((float4*)sh_ns)[2 * c + 1] = n1v;
            f[0] = n0.x; f[1] = n0.y; f[2] = n0.z; f[3] = n0.w;
            f[4] = n1v.x; f[5] = n1v.y; f[6] = n1v.z; f[7] = n1v.w;
            unsigned long long ka[8] = {
                U64KEY(A0.x, A0.y), U64KEY(A0.z, A0.w),
                U64KEY(A1.x, A1.y), U64KEY(A1.z, A1.w),
                U64KEY(A2.x, A2.y), U64KEY(A2.z, A2.w),
                U64KEY(A3.x, A3.y), U64KEY(A3.z, A3.w)};
            unsigned long long kb[8] = {
                U64KEY(B0.x, B0.y), U64KEY(B0.z, B0.w),
                U64KEY(B1.x, B1.y), U64KEY(B1.z, B1.w),
                U64KEY(B2.x, B2.y), U64KEY(B2.z, B2.w),
                U64KEY(B3.x, B3.y), U64KEY(B3.z, B3.w)};
            #pragma unroll
            for (int k = 0; k < 8; ++k) {
                unsigned long long kk = ka[k] > kb[k] ? ka[k] : kb[k];
                unsigned int ub = (unsigned int)(kk >> 32);
                sh_idx[c * 8 + k] = (unsigned char)(127u - ((unsigned int)kk & 127u));
                if (ub > 0x3F000000u) {             // best > 0.5f
                    pb |= (1u << k);
                    atomicAdd(&hist2[bkt1024(f[k])], 1u);
                } else if (ub < 0x3F000000u) {      // best < 0.5f (best >= 0)
                    nb |= (1u << k);
                    atomicAdd(&hist[bkt1024(f[k])], 1u);
                }
            }
            posmask[c] = (unsigned char)pb;
            negmask[c] = (unsigned char)nb;
        }
        if (tid < 16) {                            // tail chunks 1024..1039
            const int c = 1024 + tid;
            const uint4* a4 = (const uint4*)(P0 + (size_t)c * 8);
            const uint4* b4 = (const uint4*)(P1 + (size_t)c * 8);
            uint4 A0 = a4[0], A1 = a4[1], A2 = a4[2], A3 = a4[3];
            uint4 B0 = b4[0], B1 = b4[1], B2 = b4[2], B3 = b4[3];
            float4 n0 = ns4[2 * c], n1v = ns4[2 * c + 1];
            ((float4*)sh_ns)[2 * c] = n0;
            ((float4*)sh_ns)[2 * c + 1] = n1v;
            float ft[8] = {n0.x, n0.y, n0.z, n0.w, n1v.x, n1v.y, n1v.z, n1v.w};
            unsigned long long ka[8] = {
                U64KEY(A0.x, A0.y), U64KEY(A0.z, A0.w),
                U64KEY(A1.x, A1.y), U64KEY(A1.z, A1.w),
                U64KEY(A2.x, A2.y), U64KEY(A2.z, A2.w),
                U64KEY(A3.x, A3.y), U64KEY(A3.z, A3.w)};
            unsigned long long kb[8] = {
                U64KEY(B0.x, B0.y), U64KEY(B0.z, B0.w),
                U64KEY(B1.x, B1.y), U64KEY(B1.z, B1.w),
                U64KEY(B2.x, B2.y), U64KEY(B2.z, B2.w),
                U64KEY(B3.x, B3.y), U64KEY(B3.z, B3.w)};
            unsigned int pb2 = 0, nb2 = 0;
            #pragma unroll
            for (int k = 0; k < 8; ++k) {
                unsigned long long kk = ka[k] > kb[k] ? ka[k] : kb[k];
                unsigned int ub = (unsigned int)(kk >> 32);
                sh_idx[c * 8 + k] = (unsigned char)(127u - ((unsigned int)kk & 127u));
                if (ub > 0x3F000000u) {
                    pb2 |= (1u << k);
                    atomicAdd(&hist2[bkt1024(ft[k])], 1u);
                } else if (ub < 0x3F000000u) {
                    nb2 |= (1u << k);
                    atomicAdd(&hist[bkt1024(ft[k])], 1u);
                }
            }
            posmask[c] = (unsigned char)pb2;
            negmask[c] = (unsigned char)nb2;
        }
    }
    __syncthreads();

    // ---- suffix scans: wave 0 -> hist (neg), wave 1 -> hist2 (pos) ---------
    {
        const int wv = tid >> 6, ln = tid & 63;
        if (wv < 2) {
            unsigned int* H = wv ? hist2 : hist;
            unsigned int s[16];
            #pragma unroll
            for (int k = 0; k < 16; ++k) {
                unsigned int v = H[k * 64 + ln];
                #pragma unroll
                for (int off = 1; off < 64; off <<= 1) {
                    unsigned int o = __shfl_down(v, off, 64);
                    if (ln + off < 64) v += o;
                }
                s[k] = v;
            }
            unsigned int after = 0;
            #pragma unroll
            for (int k = 15; k >= 0; --k) {
                unsigned int tot = __shfl(s[k], 0, 64);
                H[k * 64 + ln] = s[k] + after;
                after += tot;
            }
        }
    }
    __syncthreads();
    const unsigned int nneg = hist[0];
    const unsigned int npos = hist2[0];

    // ---- kth = 128th-largest pos noise (capacity-free, exact) --------------
    if (npos >= MAX_FG) {                       // block-uniform branch
        {
            unsigned int S  = hist2[tid];
            unsigned int Sn = (tid < 1023) ? hist2[tid + 1] : 0;
            if (S >= MAX_FG && Sn < MAX_FG) { sh_Bp = tid; sh_needp = MAX_FG - Sn; }
        }
        __syncthreads();
        const unsigned int Bp = sh_Bp, needp = sh_needp;
        #pragma unroll
        for (int k = 0; k < 8; ++k) {
            if (((pb >> k) & 1u) && bkt1024(f[k]) == Bp) {
                unsigned int slot = atomicAdd(&sh_cc, 1u);
                if (slot < C_CAP) C[slot] = f[k];
            }
        }
        if (tid < 16) {
            unsigned int pb2 = posmask[1024 + tid];
            #pragma unroll
            for (int k = 0; k < 8; ++k) {
                if ((pb2 >> k) & 1u) {
                    float v = sh_ns[(1024 + tid) * 8 + k];
                    if (bkt1024(v) == Bp) {
                        unsigned int slot = atomicAdd(&sh_cc, 1u);
                        if (slot < C_CAP) C[slot] = v;
                    }
                }
            }
        }
        __syncthreads();
        {   // exact in-bucket value rank: v with #greater < needp <= #greater+#eq
            unsigned int cc = min(sh_cc, (unsigned int)C_CAP);
            if (tid < (int)cc) {
                float my = C[tid];
                unsigned int g = 0, e = 0;
                for (unsigned int j = 0; j < cc; ++j) {
                    float v = C[j];
                    g += (v > my) ? 1u : 0u;
                    e += (v == my) ? 1u : 0u;
                }
                if (g < needp && g + e >= needp) sh_kth = __float_as_uint(my);
            }
        }
        __syncthreads();
    }
    const float kthf = __uint_as_float(sh_kth);

    // ---- selp collection: pos && ns >= kth; store key = bits(2+ns) ---------
    #pragma unroll
    for (int k = 0; k < 8; ++k) {
        if (((pb >> k) & 1u) && f[k] >= kthf) {
            unsigned int slot = atomicAdd(&sh_n1a, 1u);
            if (slot < S_CAP) {
                skey[slot] = __float_as_uint(__fadd_rn(2.0f, f[k]));
                sm[slot]   = (unsigned short)(tid * 8 + k);
            }
        }
    }
    if (tid < 16) {
        unsigned int pb2 = posmask[1024 + tid];
        #pragma unroll
        for (int k = 0; k < 8; ++k) {
            if ((pb2 >> k) & 1u) {
                int m = (1024 + tid) * 8 + k;
                float v = sh_ns[m];
                if (v >= kthf) {
                    unsigned int slot = atomicAdd(&sh_n1a, 1u);
                    if (slot < S_CAP) {
                        skey[slot] = __float_as_uint(__fadd_rn(2.0f, v));
                        sm[slot]   = (unsigned short)m;
                    }
                }
            }
        }
    }
    __syncthreads();
    const unsigned int n1 = min(sh_n1a, (unsigned int)S_CAP);
    const unsigned int k2 = K_OUT - n1;         // >= 382 expected
    const bool enough_neg = (nneg >= k2);

    if (tid < 4) { skey[n1 + tid] = 0u; sm[n1 + tid] = 0xFFFFu; }  // pad
    if (enough_neg) {
        unsigned int S  = hist[tid];
        unsigned int Sn = (tid < 1023) ? hist[tid + 1] : 0;
        if (S >= k2 && Sn < k2) sh_B = tid;     // unique writer
    }   // else sh_B stays 0 -> place all negs
    __syncthreads();
    const unsigned int B1 = sh_B;

    // ---- selp exact pairwise rank (vectorized LDS reads) + fg writes -------
    if (tid < (int)n1) {
        unsigned int   ki = skey[tid];
        unsigned short mi = sm[tid];
        unsigned int r = 0;
        for (unsigned int j = 0; j < n1; j += 4) {
            uint4   kv = *(const uint4*)&skey[j];
            ushort4 mv = *(const ushort4*)&sm[j];
            r += (kv.x > ki || (kv.x == ki && mv.x < mi)) ? 1u : 0u;
            r += (kv.y > ki || (kv.y == ki && mv.y < mi)) ? 1u : 0u;
            r += (kv.z > ki || (kv.z == ki && mv.z < mi)) ? 1u : 0u;
            r += (kv.w > ki || (kv.w == ki && mv.w < mi)) ? 1u : 0u;
        }
        int mi_ = mi;
        int lbl = sh_idx[mi_];
        float4 roi = (mi_ < NBOX) ? ((const float4*)boxes)[b * NBOX + mi_]
                                  : sgt[mi_ - NBOX];
        ((float4*)out_bt)[b * K_OUT + r] = sgt[lbl];
        out_cls[b * K_OUT + r] = (float)slab[lbl];
        ((float4*)out_roi)[b * K_OUT + r] = roi;
        out_p2l[b * K_OUT + r] = (float)lbl;
    }

    // ---- neg bucket placement: positional, rank-exact ----------------------
    #pragma unroll
    for (int k = 0; k < 8; ++k) {
        if ((nb >> k) & 1u) {
            float v = f[k];
            unsigned int be = bkt1024(v);
            if (be >= B1) {
                unsigned int base = (be < 1023) ? hist[be + 1] : 0;
                unsigned int a = base + atomicAdd(&bctr[be], 1u);
                if (a < U_CAP) {
                    ukey[a] = __float_as_uint(v);   // v >= 0: uint-monotone
                    um[a]   = (unsigned short)(tid * 8 + k);
                }
            }
        }
    }
    if (tid < 16) {
        unsigned int nb2 = negmask[1024 + tid];
        #pragma unroll
        for (int k = 0; k < 8; ++k) {
            if ((nb2 >> k) & 1u) {
                int m = (1024 + tid) * 8 + k;
                float v = sh_ns[m];
                unsigned int be = bkt1024(v);
                if (be >= B1) {
                    unsigned int base = (be < 1023) ? hist[be + 1] : 0;
                    unsigned int a = base + atomicAdd(&bctr[be], 1u);
                    if (a < U_CAP) {
                        ukey[a] = __float_as_uint(v);
                        um[a]   = (unsigned short)m;
                    }
                }
            }
        }
    }
    __syncthreads();

    // ---- neg finalize: within-bucket exact rank over own segment -----------
    const unsigned int q = min(hist[B1], (unsigned int)U_CAP);
    for (unsigned int a = tid; a < q; a += 1024) {
        unsigned int   ki = ukey[a];
        unsigned short mi = um[a];
        unsigned int be = bkt1024(__uint_as_float(ki));
        unsigned int base = (be < 1023) ? hist[be + 1] : 0;
        unsigned int end  = min(hist[be], q);
        unsigned int r = base;
        for (unsigned int j = base; j < end; ++j) {
            unsigned int kj = ukey[j];
            if (kj > ki || (kj == ki && um[j] < mi)) ++r;
        }
        if (r < k2) {
            float4 roi = (mi < NBOX) ? ((const float4*)boxes)[b * NBOX + mi]
                                     : sgt[mi - NBOX];
            unsigned int gr = n1 + r;
            ((float4*)out_bt)[b * K_OUT + gr] = make_float4(0.f, 0.f, 0.f, 0.f);
            out_cls[b * K_OUT + gr] = 0.0f;
            ((float4*)out_roi)[b * K_OUT + gr] = roi;
            out_p2l[b * K_OUT + gr] = 0.0f;
        }
    }

    // ---- fallback (statistically impossible: nneg < k2): rest by m asc -----
    if (!enough_neg) {
        __syncthreads();
        const unsigned int k3 = k2 - nneg;
        for (int m = tid; m < M; m += 1024) {
            if (((posmask[m >> 3] >> (m & 7)) & 1) && sh_ns[m] < kthf) {
                unsigned int r = 0;
                for (int m2 = 0; m2 < m; ++m2)
                    if (((posmask[m2 >> 3] >> (m2 & 7)) & 1) && sh_ns[m2] < kthf) ++r;
                if (r < k3) {
                    int lbl = sh_idx[m];
                    float4 roi = (m < NBOX) ? ((const float4*)boxes)[b * NBOX + m]
                                            : sgt[m - NBOX];
                    unsigned int gr = n1 + nneg + r;
                    ((float4*)out_bt)[b * K_OUT + gr] = sgt[lbl];
                    out_cls[b * K_OUT + gr] = (float)slab[lbl];
                    ((float4*)out_roi)[b * K_OUT + gr] = roi;
                    out_p2l[b * K_OUT + gr] = (float)lbl;
                }
            }
        }
    }
}

extern "C" void kernel_launch(void* const* d_in, const int* in_sizes, int n_in,
                              void* d_out, int out_size, void* d_ws, size_t ws_size,
                              hipStream_t stream) {
    const float* boxes     = (const float*)d_in[0];
    const float* gt_boxes  = (const float*)d_in[1];
    const int*   gt_labels = (const int*)d_in[2];
    const float* noise     = (const float*)d_in[3];
    unsigned long long* part = (unsigned long long*)d_ws;  // GSPLIT*B*M u64 = 4.26 MB
    float* out = (float*)d_out;

    iou_kernel<<<BATCH * IOU_CB * GSPLIT, IOU_TPB, 0, stream>>>(boxes, gt_boxes, part);
    select_kernel<<<BATCH, 1024, 0, stream>>>(boxes, gt_boxes, gt_labels, noise,
                                              part, out);
}